// Round 13
// baseline (138.468 us; speedup 1.0000x reference)
//
#include <hip/hip_runtime.h>

#define NN 4096
#define BB 64
#define KK 128
#define EE 256
#define HTS 4352   // ht row stride (NN + 256 slack; SF K-loop may read to +191)
#define CSR 4224   // csb rows (NN + 128 slack, zeroed)
#define PCAP 160   // per-structure padded atom capacity (abase-relative)
#define YTS 264    // LDS activation row stride (u16)
#define ZTS 20     // pair LDS zt row stride (u16)
#define SFS 66     // LDS SF row stride (u16): 64 cols + 2 pad (33 dwords, odd)

typedef unsigned short u16;
typedef __bf16 bhalf;
typedef bhalf bhalf8 __attribute__((ext_vector_type(8)));
typedef float floatx4 __attribute__((ext_vector_type(4)));

__device__ __forceinline__ float b2f(u16 u) {
  union { unsigned int i; float f; } v; v.i = ((unsigned int)u) << 16; return v.f;
}
__device__ __forceinline__ u16 f2b(float f) {
  union { float f; unsigned int i; } v; v.f = f;
  unsigned int r = (v.i + 0x7FFFu + ((v.i >> 16) & 1u)) >> 16;
  return (u16)r;
}
__device__ __forceinline__ float silu_f(float v) {
  return v / (1.f + __expf(-v));
}
// 8 consecutive f32 -> bf16x8 fragment
__device__ __forceinline__ bhalf8 ld8f(const float* __restrict__ p) {
  float4 f0 = *(const float4*)p;
  float4 f1 = *(const float4*)(p + 4);
  union { bhalf8 v; u16 s[8]; } u;
  u.s[0] = f2b(f0.x); u.s[1] = f2b(f0.y); u.s[2] = f2b(f0.z); u.s[3] = f2b(f0.w);
  u.s[4] = f2b(f1.x); u.s[5] = f2b(f1.y); u.s[6] = f2b(f1.z); u.s[7] = f2b(f1.w);
  return u.v;
}

// Swizzled weight layout: Wsw[nt*4096 + k*512 + lane*8 + i] = W[(nt*16+r)*256 + q*8 + k*32 + i]

// ================= P1: weight swizzle-casts + kft + csb-zero + seg + dot ====
__global__ __launch_bounds__(256) void p1_k(
    const float* __restrict__ Wpre, const float* __restrict__ W0,
    const float* __restrict__ Wres, const float* __restrict__ Wup,
    const float* __restrict__ Wdn, const int* __restrict__ bs,
    const float* __restrict__ x, const float* __restrict__ kvec,
    u16* __restrict__ wpre, u16* __restrict__ w0b, u16* __restrict__ wrb,
    float* __restrict__ kft, u16* __restrict__ csb,
    int* __restrict__ seg, float* __restrict__ dout)
{
  int bid = blockIdx.x, tid = threadIdx.x;
  if (bid < 288) {
    int mat = bid >> 5;
    int w8 = ((bid & 31) * 256 + tid);
    int o = w8 * 8;
    int lane = w8 & 63, k = (w8 >> 6) & 7, nt = w8 >> 9;
    int r = lane & 15, q = lane >> 4;
    int src = (nt * 16 + r) * 256 + q * 8 + k * 32;
    const float* S; u16* D;
    if (mat < 2)      { S = Wpre + mat * 65536;       D = wpre + mat * 65536; }
    else if (mat == 2){ S = W0;                       D = w0b; }
    else              { S = Wres + (mat - 3) * 65536; D = wrb + (mat - 3) * 65536; }
    *(bhalf8*)(D + o) = ld8f(S + src);
  }
  else if (bid < 416) {
    int i = (bid - 288) * 256 + tid;          // kft[e][kk]
    int e = i >> 7, kk = i & 127;
    float a = 0.f;
#pragma unroll
    for (int d = 0; d < 8; ++d) a += Wup[e * 8 + d] * Wdn[d * KK + kk];
    kft[i] = a;
  } else if (bid < 424) {
    int base = 4096 * 256 + ((bid - 416) * 256 + tid) * 16;
    uint4 z = {0, 0, 0, 0};
    *(uint4*)(csb + base) = z;
    *(uint4*)(csb + base + 8) = z;
  } else if (bid == 424) {
    int b = tid;
    if (b <= BB) {
      int lo = 0, hi = NN;
      while (lo < hi) { int mid = (lo + hi) >> 1; if (bs[mid] < b) lo = mid + 1; else hi = mid; }
      seg[b] = lo;
    }
  } else {
    int i = (bid - 425) * 256 + tid;          // dot: n*128 + kk
    int n = i >> 7, kk = i & 127;
    int b = bs[n];
    const float* kp = kvec + (b * KK + kk) * 3;
    const float* xp = x + n * 3;
    float d = kp[0] * xp[0] + kp[1] * xp[1] + kp[2] * xp[2];
    float sv, cv;
    __sincosf(d, &sv, &cv);
    dout[i] = d;
    csb[(n << 8) + kk] = f2b(cv);
    csb[(n << 8) + 128 + kk] = f2b(sv);
  }
}

// ================= P2: pre-residual pair (-> ht, transposed) + csb->ctb transpose =================
__global__ __launch_bounds__(256) void p2_k(
    const float* __restrict__ h, const u16* __restrict__ Wa, const u16* __restrict__ Wb,
    u16* __restrict__ ht,
    const u16* __restrict__ csb, const int* __restrict__ seg, u16* __restrict__ ctb)
{
  __shared__ u16 sh[8256];
  if (blockIdx.x < 256) {
    const int lane = threadIdx.x & 63, wv = threadIdx.x >> 6;
    const int m0 = blockIdx.x * 16;
    const int n0 = wv * 64;
    const int r = lane & 15, q = lane >> 4;
    const int lane8 = lane * 8;
    const float* Ap = h + (m0 + r) * EE + q * 8;
    floatx4 acc[4];
#pragma unroll
    for (int t = 0; t < 4; ++t) acc[t] = (floatx4){0.f, 0.f, 0.f, 0.f};
#pragma unroll
    for (int k = 0; k < 8; ++k) {
      bhalf8 av = ld8f(Ap + k * 32);
#pragma unroll
      for (int t = 0; t < 4; ++t) {
        bhalf8 bv = *(const bhalf8*)(Wa + ((wv * 4 + t) * 8 + k) * 512 + lane8);
        acc[t] = __builtin_amdgcn_mfma_f32_16x16x32_bf16(av, bv, acc[t], 0, 0, 0);
      }
    }
#pragma unroll
    for (int t = 0; t < 4; ++t) {
      int col = n0 + t * 16 + r;
#pragma unroll
      for (int i = 0; i < 4; ++i)
        sh[(q * 4 + i) * YTS + col] = f2b(silu_f(acc[t][i]));
    }
    __syncthreads();
#pragma unroll
    for (int t = 0; t < 4; ++t) acc[t] = (floatx4){0.f, 0.f, 0.f, 0.f};
#pragma unroll
    for (int k = 0; k < 8; ++k) {
      bhalf8 av = *(const bhalf8*)(&sh[r * YTS + q * 8 + k * 32]);
#pragma unroll
      for (int t = 0; t < 4; ++t) {
        bhalf8 bv = *(const bhalf8*)(Wb + ((wv * 4 + t) * 8 + k) * 512 + lane8);
        acc[t] = __builtin_amdgcn_mfma_f32_16x16x32_bf16(av, bv, acc[t], 0, 0, 0);
      }
    }
    __syncthreads();
#pragma unroll
    for (int t = 0; t < 4; ++t) {
      int col = n0 + t * 16 + r;
#pragma unroll
      for (int i = 0; i < 4; ++i) {
        int g = m0 + q * 4 + i;
        float v = silu_f(acc[t][i]) + h[g * EE + col];
        sh[col * ZTS + q * 4 + i] = f2b(v);
      }
    }
    __syncthreads();
    int e = threadIdx.x;
    const uint2* src = (const uint2*)&sh[e * ZTS];
    uint2* dst = (uint2*)(ht + e * HTS + m0);
#pragma unroll
    for (int i = 0; i < 4; ++i) dst[i] = src[i];
  } else {
    int bid2 = blockIdx.x - 256;
    int b = bid2 / 5, p0 = (bid2 % 5) * 32, t = threadIdx.x;
    int s0 = seg[b], s1 = seg[b + 1];
    int abase = s0 & ~7;
#pragma unroll
    for (int it = 0; it < 32; ++it) {
      int idx = it * 256 + t;
      int pl = idx >> 8, j = idx & 255;
      int n = abase + p0 + pl;
      u16 v = 0;
      if (n >= s0 && n < s1) v = csb[(n << 8) | j];
      sh[pl * 258 + j] = v;
    }
    __syncthreads();
    unsigned w[16];
#pragma unroll
    for (int i = 0; i < 16; ++i) {
      unsigned lo = sh[(2 * i) * 258 + t];
      unsigned hi = sh[(2 * i + 1) * 258 + t];
      w[i] = lo | (hi << 16);
    }
    uint4* dst = (uint4*)(ctb + ((b << 8) + t) * PCAP + p0);
#pragma unroll
    for (int i = 0; i < 4; ++i) {
      uint4 u; u.x = w[4*i]; u.y = w[4*i+1]; u.z = w[4*i+2]; u.w = w[4*i+3];
      dst[i] = u;
    }
  }
}

// ================= P3: fused SF + hupd + full update-MLP =================
// 256 blocks x 512 threads (1 block/CU); block owns atom rows 16b..16b+16.
// Per overlapping structure s: for each j-quarter (64 cols), 8 waves compute
// the SF tile (256e x 64j) = kft .* (ht @ ctb^T) into LDS, then accumulate the
// u-GEMM partial u[n,e] += cs[n,jq] @ SF[e,jq]^T in registers. After all
// quarters: masked rows -> A0; then the 7-stage MLP (register weight dbuf).
__device__ __forceinline__ void loadB(const u16* __restrict__ W, int wv, int lane8,
                                      bhalf8 (&bf)[8][2]) {
#pragma unroll
  for (int k = 0; k < 8; ++k)
#pragma unroll
    for (int t = 0; t < 2; ++t)
      bf[k][t] = *(const bhalf8*)(W + ((wv * 2 + t) * 8 + k) * 512 + lane8);
}

__device__ __forceinline__ void stageD(
    const u16* __restrict__ As, const bhalf8 (&B)[8][2],
    const u16* __restrict__ Wn, bhalf8 (&Bn)[8][2],
    u16* __restrict__ Ad, const u16* __restrict__ Ask,
    float* __restrict__ outg, int R0, int c0, int r, int q, int wv, int lane8)
{
  if (Wn) loadB(Wn, wv, lane8, Bn);
  bhalf8 a[8];
#pragma unroll
  for (int k = 0; k < 8; ++k)
    a[k] = *(const bhalf8*)(As + r * YTS + q * 8 + k * 32);
  floatx4 acc[2];
  acc[0] = (floatx4){0.f, 0.f, 0.f, 0.f};
  acc[1] = (floatx4){0.f, 0.f, 0.f, 0.f};
#pragma unroll
  for (int k = 0; k < 8; ++k) {
    acc[0] = __builtin_amdgcn_mfma_f32_16x16x32_bf16(a[k], B[k][0], acc[0], 0, 0, 0);
    acc[1] = __builtin_amdgcn_mfma_f32_16x16x32_bf16(a[k], B[k][1], acc[1], 0, 0, 0);
  }
#pragma unroll
  for (int t = 0; t < 2; ++t) {
    int col = c0 + t * 16 + r;
#pragma unroll
    for (int i = 0; i < 4; ++i) {
      int row = q * 4 + i;
      float v = silu_f(acc[t][i]);
      if (Ask) v += b2f(Ask[row * YTS + col]);
      if (outg) outg[(R0 + row) * EE + col] = v;
      else      Ad[row * YTS + col] = f2b(v);
    }
  }
}

__global__ __launch_bounds__(512) void tail_k(
    const u16* __restrict__ csb, const u16* __restrict__ ht,
    const u16* __restrict__ ctb, const float* __restrict__ kft,
    const int* __restrict__ bs, const int* __restrict__ seg,
    const u16* __restrict__ w0b, const u16* __restrict__ wrb,
    float* __restrict__ out)
{
  __shared__ u16 SF[256 * SFS];                 // 33.8 KB
  __shared__ u16 A0[16 * YTS], A1[16 * YTS];    // 16.9 KB
  const int R0 = blockIdx.x * 16;
  const int lane = threadIdx.x & 63, wv = threadIdx.x >> 6;  // 8 waves
  const int r = lane & 15, q = lane >> 4;
  const int c0 = wv * 32;       // u-GEMM e-columns
  const int e0w = wv * 32;      // SF e-slice
  const int lane8 = lane * 8;

  int s = bs[R0];
  while (true) {
    const int abase = seg[s] & ~7;
    const int phi = seg[s + 1] - abase;         // <= PCAP
    floatx4 accu[2];
    accu[0] = (floatx4){0.f, 0.f, 0.f, 0.f};
    accu[1] = (floatx4){0.f, 0.f, 0.f, 0.f};
#pragma unroll
    for (int jq = 0; jq < 4; ++jq) {
      const int j0 = jq * 64;
      // hoisted loads: kft for this wave's SF outputs + u-stage A-fragments
      float kf[2][4][4];
#pragma unroll
      for (int m = 0; m < 2; ++m)
#pragma unroll
        for (int t = 0; t < 4; ++t) {
          int kk = (j0 + t * 16 + r) & 127;
#pragma unroll
          for (int i = 0; i < 4; ++i)
            kf[m][t][i] = kft[(e0w + m * 16 + q * 4 + i) * KK + kk];
        }
      bhalf8 au0 = *(const bhalf8*)(csb + (R0 + r) * 256 + j0 + q * 8);
      bhalf8 au1 = *(const bhalf8*)(csb + (R0 + r) * 256 + j0 + q * 8 + 32);
      // ---- SF quarter: 256e x 64j ----
      {
        const u16* Ap = ht + (e0w + r) * HTS + abase + q * 8;
        const u16* Bp = ctb + ((s << 8) + j0 + r) * PCAP + q * 8;
        floatx4 acc[2][4];
#pragma unroll
        for (int m = 0; m < 2; ++m)
#pragma unroll
          for (int t = 0; t < 4; ++t) acc[m][t] = (floatx4){0.f, 0.f, 0.f, 0.f};
        for (int p0 = 0; p0 < phi; p0 += 32) {
          bhalf8 a0 = *(const bhalf8*)(Ap + p0);
          bhalf8 a1 = *(const bhalf8*)(Ap + 16 * HTS + p0);
#pragma unroll
          for (int t = 0; t < 4; ++t) {
            bhalf8 bv = *(const bhalf8*)(Bp + t * 16 * PCAP + p0);
            acc[0][t] = __builtin_amdgcn_mfma_f32_16x16x32_bf16(a0, bv, acc[0][t], 0, 0, 0);
            acc[1][t] = __builtin_amdgcn_mfma_f32_16x16x32_bf16(a1, bv, acc[1][t], 0, 0, 0);
          }
        }
#pragma unroll
        for (int m = 0; m < 2; ++m)
#pragma unroll
          for (int t = 0; t < 4; ++t)
#pragma unroll
            for (int i = 0; i < 4; ++i)
              SF[(e0w + m * 16 + q * 4 + i) * SFS + t * 16 + r] =
                  f2b(acc[m][t][i] * kf[m][t][i]);
      }
      __syncthreads();
      // ---- u partial: rows R0.., e-cols c0.., K = this j-quarter (64) ----
#pragma unroll
      for (int t = 0; t < 2; ++t) {
        bhalf8 b0 = *(const bhalf8*)(&SF[(c0 + t * 16 + r) * SFS + q * 8]);
        bhalf8 b1 = *(const bhalf8*)(&SF[(c0 + t * 16 + r) * SFS + q * 8 + 32]);
        accu[t] = __builtin_amdgcn_mfma_f32_16x16x32_bf16(au0, b0, accu[t], 0, 0, 0);
        accu[t] = __builtin_amdgcn_mfma_f32_16x16x32_bf16(au1, b1, accu[t], 0, 0, 0);
      }
      __syncthreads();   // before next quarter overwrites SF
    }
    // masked write of this structure's rows
    int lo = seg[s] - R0;     if (lo < 0)  lo = 0;
    int hi = seg[s + 1] - R0; if (hi > 16) hi = 16;
#pragma unroll
    for (int t = 0; t < 2; ++t) {
      int col = c0 + t * 16 + r;
#pragma unroll
      for (int i = 0; i < 4; ++i) {
        int row = q * 4 + i;
        if (row >= lo && row < hi)
          A0[row * YTS + col] = f2b(0.01f * accu[t][i]);
      }
    }
    if (seg[s + 1] >= R0 + 16) break;
    ++s;
  }
  bhalf8 B0[8][2], B1[8][2];
  loadB(w0b, wv, lane8, B0);     // stage-y weights in flight across the barrier
  __syncthreads();
  stageD(A0, B0, wrb + 0 * EE * EE, B1, A1, nullptr, nullptr, R0, c0, r, q, wv, lane8); // y
  __syncthreads();
  stageD(A1, B1, wrb + 1 * EE * EE, B0, A0, nullptr, nullptr, R0, c0, r, q, wv, lane8); // z1
  __syncthreads();
  stageD(A0, B0, wrb + 2 * EE * EE, B1, A1, A1,      nullptr, R0, c0, r, q, wv, lane8); // t1
  __syncthreads();
  stageD(A1, B1, wrb + 3 * EE * EE, B0, A0, nullptr, nullptr, R0, c0, r, q, wv, lane8); // z2
  __syncthreads();
  stageD(A0, B0, wrb + 4 * EE * EE, B1, A1, A1,      nullptr, R0, c0, r, q, wv, lane8); // t2
  __syncthreads();
  stageD(A1, B1, wrb + 5 * EE * EE, B0, A0, nullptr, nullptr, R0, c0, r, q, wv, lane8); // z3
  __syncthreads();
  stageD(A0, B0, nullptr,           B1, nullptr, A1, out,     R0, c0, r, q, wv, lane8); // out
}

extern "C" void kernel_launch(void* const* d_in, const int* in_sizes, int n_in,
                              void* d_out, int out_size, void* d_ws, size_t ws_size,
                              hipStream_t stream) {
  const float* h    = (const float*)d_in[0];
  const float* x    = (const float*)d_in[1];
  const float* kv   = (const float*)d_in[2];
  const int*   bs   = (const int*)d_in[3];
  const float* Wpre = (const float*)d_in[5];
  const float* Wdn  = (const float*)d_in[6];
  const float* Wup  = (const float*)d_in[7];
  const float* W0   = (const float*)d_in[8];
  const float* Wres = (const float*)d_in[9];
  float* out = (float*)d_out;          // [0, N*E) = hu, [N*E, ..) = dot

  float* kft = (float*)d_ws;                  // 256*128
  int*   seg = (int*)(kft + EE * KK);         // 128
  u16* wpre = (u16*)(seg + 128);              // 2*E*E (swizzled)
  u16* w0b  = wpre + 2 * EE * EE;             // E*E   (swizzled)
  u16* wrb  = w0b + EE * EE;                  // 6*E*E (swizzled)
  u16* csb  = wrb + 6 * EE * EE;              // CSR*256 (slack rows zeroed)
  u16* ctb  = csb + CSR * 256;                // B*256*PCAP
  u16* ht   = ctb + BB * 256 * PCAP;          // 256*HTS

  p1_k<<<2473, 256, 0, stream>>>(Wpre, W0, Wres, Wup, Wdn, bs, x, kv,
                                 wpre, w0b, wrb, kft, csb, seg, out + NN * EE);
  p2_k<<<576, 256, 0, stream>>>(h, wpre, wpre + EE * EE, ht, csb, seg, ctb);
  tail_k<<<256, 512, 0, stream>>>(csb, ht, ctb, kft, bs, seg, w0b, wrb, out);
}

// Round 14
// 121.091 us; speedup vs baseline: 1.1435x; 1.1435x over previous
//
#include <hip/hip_runtime.h>

#define NN 4096
#define BB 64
#define KK 128
#define EE 256
#define HTS 4352   // ht row stride (NN + 256 slack; sf_k K-loop may read to +191)
#define CSR 4224   // csb rows (NN + 128 slack, zeroed)
#define PCAP 160   // per-structure padded atom capacity (abase-relative)
#define YTS 264    // LDS activation row stride (u16)
#define ZTS 20     // pair LDS zt row stride (u16)

typedef unsigned short u16;
typedef __bf16 bhalf;
typedef bhalf bhalf8 __attribute__((ext_vector_type(8)));
typedef float floatx4 __attribute__((ext_vector_type(4)));

__device__ __forceinline__ float b2f(u16 u) {
  union { unsigned int i; float f; } v; v.i = ((unsigned int)u) << 16; return v.f;
}
__device__ __forceinline__ u16 f2b(float f) {
  union { float f; unsigned int i; } v; v.f = f;
  unsigned int r = (v.i + 0x7FFFu + ((v.i >> 16) & 1u)) >> 16;
  return (u16)r;
}
__device__ __forceinline__ float silu_f(float v) {
  return v / (1.f + __expf(-v));
}
// 8 consecutive f32 -> bf16x8 fragment
__device__ __forceinline__ bhalf8 ld8f(const float* __restrict__ p) {
  float4 f0 = *(const float4*)p;
  float4 f1 = *(const float4*)(p + 4);
  union { bhalf8 v; u16 s[8]; } u;
  u.s[0] = f2b(f0.x); u.s[1] = f2b(f0.y); u.s[2] = f2b(f0.z); u.s[3] = f2b(f0.w);
  u.s[4] = f2b(f1.x); u.s[5] = f2b(f1.y); u.s[6] = f2b(f1.z); u.s[7] = f2b(f1.w);
  return u.v;
}

// Swizzled weight layout: Wsw[nt*4096 + k*512 + lane*8 + i] = W[(nt*16+r)*256 + q*8 + k*32 + i]
// (nt = 16-col tile, k = K-step, lane = r + 16q): wave B-fragment load = 1 KB contiguous.

// ================= P1: weight swizzle-casts + kft + csb-zero + seg + dot (2 kk/thread) ====
__global__ __launch_bounds__(256) void p1_k(
    const float* __restrict__ Wpre, const float* __restrict__ W0,
    const float* __restrict__ Wres, const float* __restrict__ Wup,
    const float* __restrict__ Wdn, const int* __restrict__ bs,
    const float* __restrict__ x, const float* __restrict__ kvec,
    u16* __restrict__ wpre, u16* __restrict__ w0b, u16* __restrict__ wrb,
    float* __restrict__ kft, u16* __restrict__ csb,
    int* __restrict__ seg, float* __restrict__ dout)
{
  int bid = blockIdx.x, tid = threadIdx.x;
  if (bid < 288) {
    // swizzled weight casts: 9 matrices x 65536 elems, 32 blocks each, 8 elems/thread
    int mat = bid >> 5;                       // 0..8
    int w8 = ((bid & 31) * 256 + tid);        // fragment index 0..8191
    int o = w8 * 8;                           // dst offset
    int lane = w8 & 63, k = (w8 >> 6) & 7, nt = w8 >> 9;
    int r = lane & 15, q = lane >> 4;
    int src = (nt * 16 + r) * 256 + q * 8 + k * 32;
    const float* S; u16* D;
    if (mat < 2)      { S = Wpre + mat * 65536;       D = wpre + mat * 65536; }
    else if (mat == 2){ S = W0;                       D = w0b; }
    else              { S = Wres + (mat - 3) * 65536; D = wrb + (mat - 3) * 65536; }
    *(bhalf8*)(D + o) = ld8f(S + src);
  }
  else if (bid < 416) {
    int i = (bid - 288) * 256 + tid;          // kft[e][kk]
    int e = i >> 7, kk = i & 127;
    float a = 0.f;
#pragma unroll
    for (int d = 0; d < 8; ++d) a += Wup[e * 8 + d] * Wdn[d * KK + kk];
    kft[i] = a;
  } else if (bid < 424) {
    // zero csb rows [4096, 4224): 32768 u16, 8 blocks, 16 u16/thread
    int base = 4096 * 256 + ((bid - 416) * 256 + tid) * 16;
    uint4 z = {0, 0, 0, 0};
    *(uint4*)(csb + base) = z;
    *(uint4*)(csb + base + 8) = z;
  } else if (bid == 424) {
    int b = tid;
    if (b <= BB) {
      int lo = 0, hi = NN;
      while (lo < hi) { int mid = (lo + hi) >> 1; if (bs[mid] < b) lo = mid + 1; else hi = mid; }
      seg[b] = lo;
    }
  } else {
    // dot: 2 k-points per thread; i in [0, 4096*64)
    int i = (bid - 425) * 256 + tid;
    int n = i >> 6, t2 = (i & 63) << 1;
    int b = bs[n];
    const float* kp = kvec + (b * KK + t2) * 3;   // 6 contiguous floats (t2 even)
    const float* xp = x + n * 3;
    float x0 = xp[0], x1 = xp[1], x2 = xp[2];
    float2 k01 = *(const float2*)(kp);
    float2 k23 = *(const float2*)(kp + 2);
    float2 k45 = *(const float2*)(kp + 4);
    float d0 = k01.x * x0 + k01.y * x1 + k23.x * x2;
    float d1 = k23.y * x0 + k45.x * x1 + k45.y * x2;
    float s0, c0, s1, c1;
    __sincosf(d0, &s0, &c0);
    __sincosf(d1, &s1, &c1);
    float2 dp; dp.x = d0; dp.y = d1;
    *(float2*)(dout + (n << 7) + t2) = dp;
    unsigned cpack = (unsigned)f2b(c0) | ((unsigned)f2b(c1) << 16);
    unsigned spack = (unsigned)f2b(s0) | ((unsigned)f2b(s1) << 16);
    *(unsigned*)(csb + (n << 8) + t2) = cpack;
    *(unsigned*)(csb + (n << 8) + 128 + t2) = spack;
  }
}

// ================= P2: pre-residual pair (-> ht, transposed) + csb->ctb transpose =================
__global__ __launch_bounds__(256) void p2_k(
    const float* __restrict__ h, const u16* __restrict__ Wa, const u16* __restrict__ Wb,
    u16* __restrict__ ht,
    const u16* __restrict__ csb, const int* __restrict__ seg, u16* __restrict__ ctb)
{
  __shared__ u16 sh[8256];
  if (blockIdx.x < 256) {
    // ---- fused pair -> ht[e][n] = h[n][e] + silu(silu(h@Wa^T)@Wb^T) ----
    const int lane = threadIdx.x & 63, wv = threadIdx.x >> 6;
    const int m0 = blockIdx.x * 16;
    const int n0 = wv * 64;
    const int r = lane & 15, q = lane >> 4;
    const int lane8 = lane * 8;
    const float* Ap = h + (m0 + r) * EE + q * 8;
    floatx4 acc[4];
#pragma unroll
    for (int t = 0; t < 4; ++t) acc[t] = (floatx4){0.f, 0.f, 0.f, 0.f};
#pragma unroll
    for (int k = 0; k < 8; ++k) {
      bhalf8 av = ld8f(Ap + k * 32);
#pragma unroll
      for (int t = 0; t < 4; ++t) {
        bhalf8 bv = *(const bhalf8*)(Wa + ((wv * 4 + t) * 8 + k) * 512 + lane8);
        acc[t] = __builtin_amdgcn_mfma_f32_16x16x32_bf16(av, bv, acc[t], 0, 0, 0);
      }
    }
#pragma unroll
    for (int t = 0; t < 4; ++t) {
      int col = n0 + t * 16 + r;
#pragma unroll
      for (int i = 0; i < 4; ++i)
        sh[(q * 4 + i) * YTS + col] = f2b(silu_f(acc[t][i]));
    }
    __syncthreads();
#pragma unroll
    for (int t = 0; t < 4; ++t) acc[t] = (floatx4){0.f, 0.f, 0.f, 0.f};
#pragma unroll
    for (int k = 0; k < 8; ++k) {
      bhalf8 av = *(const bhalf8*)(&sh[r * YTS + q * 8 + k * 32]);
#pragma unroll
      for (int t = 0; t < 4; ++t) {
        bhalf8 bv = *(const bhalf8*)(Wb + ((wv * 4 + t) * 8 + k) * 512 + lane8);
        acc[t] = __builtin_amdgcn_mfma_f32_16x16x32_bf16(av, bv, acc[t], 0, 0, 0);
      }
    }
    __syncthreads();   // y-reads done before reusing sh as zt
#pragma unroll
    for (int t = 0; t < 4; ++t) {
      int col = n0 + t * 16 + r;
#pragma unroll
      for (int i = 0; i < 4; ++i) {
        int g = m0 + q * 4 + i;
        float v = silu_f(acc[t][i]) + h[g * EE + col];
        sh[col * ZTS + q * 4 + i] = f2b(v);
      }
    }
    __syncthreads();
    int e = threadIdx.x;
    const uint2* src = (const uint2*)&sh[e * ZTS];
    uint2* dst = (uint2*)(ht + e * HTS + m0);
#pragma unroll
    for (int i = 0; i < 4; ++i) dst[i] = src[i];
  } else {
    // ---- ctb[b][j][p] = csb[abase+p][j] (zero outside segment) ----
    int bid2 = blockIdx.x - 256;
    int b = bid2 / 5, p0 = (bid2 % 5) * 32, t = threadIdx.x;
    int s0 = seg[b], s1 = seg[b + 1];
    int abase = s0 & ~7;
#pragma unroll
    for (int it = 0; it < 32; ++it) {
      int idx = it * 256 + t;
      int pl = idx >> 8, j = idx & 255;
      int n = abase + p0 + pl;
      u16 v = 0;
      if (n >= s0 && n < s1) v = csb[(n << 8) | j];
      sh[pl * 258 + j] = v;
    }
    __syncthreads();
    unsigned w[16];
#pragma unroll
    for (int i = 0; i < 16; ++i) {
      unsigned lo = sh[(2 * i) * 258 + t];
      unsigned hi = sh[(2 * i + 1) * 258 + t];
      w[i] = lo | (hi << 16);
    }
    uint4* dst = (uint4*)(ctb + ((b << 8) + t) * PCAP + p0);
#pragma unroll
    for (int i = 0; i < 4; ++i) {
      uint4 u; u.x = w[4*i]; u.y = w[4*i+1]; u.z = w[4*i+2]; u.w = w[4*i+3];
      dst[i] = u;
    }
  }
}

// ================= P3: sf GEMM: F[b][e][j] = kft[e][j&127] * sum_p ht[e][p] * ctb[b][j][p] =================
__global__ __launch_bounds__(256) void sf_k(
    const u16* __restrict__ ht, const u16* __restrict__ ctb,
    const float* __restrict__ kft, const int* __restrict__ seg, u16* __restrict__ F)
{
  const int lane = threadIdx.x & 63;
  const int wv = threadIdx.x >> 6;
  const int b = blockIdx.x;
  const int e0 = blockIdx.y * 128 + wv * 32;
  const int j0 = blockIdx.z * 64;
  const int r = lane & 15, q = lane >> 4;
  const int abase = seg[b] & ~7;
  const int phi = seg[b + 1] - abase;         // <= 135 < PCAP
  const u16* Ap = ht + (e0 + r) * HTS + abase + q * 8;
  const u16* Bp = ctb + ((b << 8) + j0 + r) * PCAP + q * 8;
  floatx4 acc[2][4];
#pragma unroll
  for (int m = 0; m < 2; ++m)
#pragma unroll
    for (int t = 0; t < 4; ++t) acc[m][t] = (floatx4){0.f, 0.f, 0.f, 0.f};
  for (int p0 = 0; p0 < phi; p0 += 32) {
    bhalf8 a0 = *(const bhalf8*)(Ap + p0);
    bhalf8 a1 = *(const bhalf8*)(Ap + 16 * HTS + p0);
#pragma unroll
    for (int t = 0; t < 4; ++t) {
      bhalf8 bv = *(const bhalf8*)(Bp + t * 16 * PCAP + p0);
      acc[0][t] = __builtin_amdgcn_mfma_f32_16x16x32_bf16(a0, bv, acc[0][t], 0, 0, 0);
      acc[1][t] = __builtin_amdgcn_mfma_f32_16x16x32_bf16(a1, bv, acc[1][t], 0, 0, 0);
    }
  }
#pragma unroll
  for (int m = 0; m < 2; ++m)
#pragma unroll
    for (int t = 0; t < 4; ++t) {
      int col = j0 + t * 16 + r;
      int kk = col & 127;
#pragma unroll
      for (int i = 0; i < 4; ++i) {
        int row = e0 + m * 16 + q * 4 + i;    // e
        F[((b << 8) + row) * 256 + col] = f2b(acc[m][t][i] * kft[row * KK + kk]);
      }
    }
}

// ================= P4: fused hupd + full update-MLP =================
// 256 blocks x 512 threads (1 block/CU); 16-row tiles; 8 waves, wave = 16r x 32c.
// Register double-buffer of stage weights: next stage's B-fragments are loaded
// at the START of the current stage, hiding L2 latency behind MFMA + barrier.
__device__ __forceinline__ void loadB(const u16* __restrict__ W, int wv, int lane8,
                                      bhalf8 (&bf)[8][2]) {
#pragma unroll
  for (int k = 0; k < 8; ++k)
#pragma unroll
    for (int t = 0; t < 2; ++t)
      bf[k][t] = *(const bhalf8*)(W + ((wv * 2 + t) * 8 + k) * 512 + lane8);
}

__device__ __forceinline__ void stageD(
    const u16* __restrict__ As, const bhalf8 (&B)[8][2],
    const u16* __restrict__ Wn, bhalf8 (&Bn)[8][2],
    u16* __restrict__ Ad, const u16* __restrict__ Ask,
    float* __restrict__ outg, int R0, int c0, int r, int q, int wv, int lane8)
{
  if (Wn) loadB(Wn, wv, lane8, Bn);   // prefetch next stage's weights (in flight)
  bhalf8 a[8];
#pragma unroll
  for (int k = 0; k < 8; ++k)
    a[k] = *(const bhalf8*)(As + r * YTS + q * 8 + k * 32);
  floatx4 acc[2];
  acc[0] = (floatx4){0.f, 0.f, 0.f, 0.f};
  acc[1] = (floatx4){0.f, 0.f, 0.f, 0.f};
#pragma unroll
  for (int k = 0; k < 8; ++k) {
    acc[0] = __builtin_amdgcn_mfma_f32_16x16x32_bf16(a[k], B[k][0], acc[0], 0, 0, 0);
    acc[1] = __builtin_amdgcn_mfma_f32_16x16x32_bf16(a[k], B[k][1], acc[1], 0, 0, 0);
  }
#pragma unroll
  for (int t = 0; t < 2; ++t) {
    int col = c0 + t * 16 + r;
#pragma unroll
    for (int i = 0; i < 4; ++i) {
      int row = q * 4 + i;
      float v = silu_f(acc[t][i]);
      if (Ask) v += b2f(Ask[row * YTS + col]);
      if (outg) outg[(R0 + row) * EE + col] = v;
      else      Ad[row * YTS + col] = f2b(v);
    }
  }
}

__global__ __launch_bounds__(512) void tail_k(
    const u16* __restrict__ csb, const u16* __restrict__ F,
    const int* __restrict__ bs, const int* __restrict__ seg,
    const u16* __restrict__ w0b, const u16* __restrict__ wrb,
    float* __restrict__ out)
{
  __shared__ u16 A0[16 * YTS], A1[16 * YTS];
  const int R0 = blockIdx.x * 16;
  const int lane = threadIdx.x & 63, wv = threadIdx.x >> 6;  // 8 waves
  const int r = lane & 15, q = lane >> 4;
  const int c0 = wv * 32;
  const int lane8 = lane * 8;
  bhalf8 B0[8][2], B1[8][2];
  // ---- stage u: A0 = 0.01 * csb[rows] @ F[s]^T, per overlapping structure ----
  {
    const u16* Ap = csb + (R0 + r) * 256 + q * 8;
    bhalf8 a[8];
#pragma unroll
    for (int k = 0; k < 8; ++k) a[k] = *(const bhalf8*)(Ap + k * 32);
    int s = bs[R0];
    while (true) {
      const u16* Bp = F + ((s << 8) + c0 + r) * 256 + q * 8;
      bhalf8 bf[8][2];
#pragma unroll
      for (int k = 0; k < 8; ++k) {
        bf[k][0] = *(const bhalf8*)(Bp + k * 32);
        bf[k][1] = *(const bhalf8*)(Bp + 16 * 256 + k * 32);
      }
      floatx4 acc[2];
      acc[0] = (floatx4){0.f, 0.f, 0.f, 0.f};
      acc[1] = (floatx4){0.f, 0.f, 0.f, 0.f};
#pragma unroll
      for (int k = 0; k < 8; ++k) {
        acc[0] = __builtin_amdgcn_mfma_f32_16x16x32_bf16(a[k], bf[k][0], acc[0], 0, 0, 0);
        acc[1] = __builtin_amdgcn_mfma_f32_16x16x32_bf16(a[k], bf[k][1], acc[1], 0, 0, 0);
      }
      int lo = seg[s] - R0;     if (lo < 0)  lo = 0;
      int hi = seg[s + 1] - R0; if (hi > 16) hi = 16;
#pragma unroll
      for (int t = 0; t < 2; ++t) {
        int col = c0 + t * 16 + r;
#pragma unroll
        for (int i = 0; i < 4; ++i) {
          int row = q * 4 + i;
          if (row >= lo && row < hi)
            A0[row * YTS + col] = f2b(0.01f * acc[t][i]);
        }
      }
      if (seg[s + 1] >= R0 + 16) break;
      ++s;
    }
  }
  loadB(w0b, wv, lane8, B0);     // stage-y weights in flight across the barrier
  __syncthreads();
  stageD(A0, B0, wrb + 0 * EE * EE, B1, A1, nullptr, nullptr, R0, c0, r, q, wv, lane8); // y
  __syncthreads();
  stageD(A1, B1, wrb + 1 * EE * EE, B0, A0, nullptr, nullptr, R0, c0, r, q, wv, lane8); // z1
  __syncthreads();
  stageD(A0, B0, wrb + 2 * EE * EE, B1, A1, A1,      nullptr, R0, c0, r, q, wv, lane8); // t1
  __syncthreads();
  stageD(A1, B1, wrb + 3 * EE * EE, B0, A0, nullptr, nullptr, R0, c0, r, q, wv, lane8); // z2
  __syncthreads();
  stageD(A0, B0, wrb + 4 * EE * EE, B1, A1, A1,      nullptr, R0, c0, r, q, wv, lane8); // t2
  __syncthreads();
  stageD(A1, B1, wrb + 5 * EE * EE, B0, A0, nullptr, nullptr, R0, c0, r, q, wv, lane8); // z3
  __syncthreads();
  stageD(A0, B0, nullptr,           B1, nullptr, A1, out,     R0, c0, r, q, wv, lane8); // out
}

extern "C" void kernel_launch(void* const* d_in, const int* in_sizes, int n_in,
                              void* d_out, int out_size, void* d_ws, size_t ws_size,
                              hipStream_t stream) {
  const float* h    = (const float*)d_in[0];
  const float* x    = (const float*)d_in[1];
  const float* kv   = (const float*)d_in[2];
  const int*   bs   = (const int*)d_in[3];
  const float* Wpre = (const float*)d_in[5];
  const float* Wdn  = (const float*)d_in[6];
  const float* Wup  = (const float*)d_in[7];
  const float* W0   = (const float*)d_in[8];
  const float* Wres = (const float*)d_in[9];
  float* out = (float*)d_out;          // [0, N*E) = hu, [N*E, ..) = dot

  float* kft = (float*)d_ws;                  // 256*128
  int*   seg = (int*)(kft + EE * KK);         // 128
  u16* wpre = (u16*)(seg + 128);              // 2*E*E (swizzled)
  u16* w0b  = wpre + 2 * EE * EE;             // E*E   (swizzled)
  u16* wrb  = w0b + EE * EE;                  // 6*E*E (swizzled)
  u16* csb  = wrb + 6 * EE * EE;              // CSR*256 (slack rows zeroed)
  u16* ctb  = csb + CSR * 256;                // B*256*PCAP
  u16* ht   = ctb + BB * 256 * PCAP;          // 256*HTS
  u16* F    = ht + 256 * HTS;                 // B*256*256

  p1_k<<<1449, 256, 0, stream>>>(Wpre, W0, Wres, Wup, Wdn, bs, x, kv,
                                 wpre, w0b, wrb, kft, csb, seg, out + NN * EE);
  p2_k<<<576, 256, 0, stream>>>(h, wpre, wpre + EE * EE, ht, csb, seg, ctb);
  sf_k<<<dim3(BB, 2, 4), 256, 0, stream>>>(ht, ctb, kft, seg, F);
  tail_k<<<256, 512, 0, stream>>>(csb, F, bs, seg, w0b, wrb, out);
}